// Round 13
// baseline (133.253 us; speedup 1.0000x reference)
//
#include <hip/hip_runtime.h>

typedef unsigned int u32;
typedef unsigned short u16;
typedef __attribute__((ext_vector_type(8))) short bf16x8;
typedef __attribute__((ext_vector_type(4))) float f32x4;

#define T_ 2048
#define HEADS 16
#define DH 64
#define NQ (2 * HEADS * T_ * DH)  // 4194304 elems per tensor

__device__ __forceinline__ u16 f2bf(float f) {
    union { float f; u32 u; } x; x.f = f;
    return (u16)((x.u + 0x7fffu + ((x.u >> 16) & 1u)) >> 16);
}
// packed f32x2 -> bf16x2 (RNE), single HW instruction
__device__ __forceinline__ u32 pkbf(float lo, float hi) {
    u32 r;
    asm("v_cvt_pk_bf16_f32 %0, %1, %2" : "=v"(r) : "v"(lo), "v"(hi));
    return r;
}
// async global->LDS, 16B per lane: LDS dest = wave-uniform base + lane*16
__device__ __forceinline__ void gll16(const void* g, void* l) {
    __builtin_amdgcn_global_load_lds(
        (const __attribute__((address_space(1))) void*)g,
        (__attribute__((address_space(3))) void*)l, 16, 0, 0);
}

// q pre-scaled by 1/sqrt(64) * log2(e) so softmax runs in exp2 domain
#define QSCALE 0.18033688011112042f
#define DEFER_THR 8.0f

// ============ fused fp32 [rows][1024] -> bf16 tile-major pre-swizzled (3 tensors) ============
// Element (m,k): tile (mt=m>>7, kt=k>>6), r=m&127, seg=(k&63)>>3, e=k&7.
// byte off = (mt*16+kt)*16384 + r*128 + ((seg ^ (r&7))<<4) + e*2.
#define NG_X  (4096 * 128)
#define NG_WA (3072 * 128)
__global__ __launch_bounds__(256) void cvt_all(
    const float* __restrict__ x, const float* __restrict__ wa,
    const float* __restrict__ wp,
    u16* __restrict__ dx, u16* __restrict__ dwa, u16* __restrict__ dwp)
{
    int gid = blockIdx.x * 256 + threadIdx.x;
    const float* src; u16* dst;
    if (gid < NG_X)                { src = x;  dst = dx; }
    else if (gid < NG_X + NG_WA)   { src = wa; dst = dwa; gid -= NG_X; }
    else                           { src = wp; dst = dwp; gid -= NG_X + NG_WA; }
    const int m = gid >> 7, s = gid & 127;          // s: 8-elem group within row
    const int kt = s >> 3, seg = s & 7;
    const float4 a0 = *(const float4*)&src[m * 1024 + s * 8];
    const float4 a1 = *(const float4*)&src[m * 1024 + s * 8 + 4];
    uint4 t;
    t.x = pkbf(a0.x, a0.y); t.y = pkbf(a0.z, a0.w);
    t.z = pkbf(a1.x, a1.y); t.w = pkbf(a1.z, a1.w);
    const int mt = m >> 7, r = m & 127;
    char* d = (char*)dst + ((size_t)(mt * 16 + kt)) * 16384
              + r * 128 + ((seg ^ (r & 7)) << 4);
    *(uint4*)d = t;
}

// ================= MFMA GEMM via global_load_lds (m97 structure) =================
// A, B: bf16 tile-major pre-swizzled (cvt layout). 128x128 tile, BK=64,
// 4 waves (2x2), 4x4 frags mfma_f32_16x16x32_bf16, explicit LDS double-buffer.
// EPI 0: qkv epilogue (q,k [B,H,T,D], q scaled QSCALE; v transposed [B,H,D,T])
// EPI 1: proj epilogue (fp32 out + bias)
template<int EPI>
__global__ __launch_bounds__(256, 2) void gemm_lds(
    const char* __restrict__ At, const char* __restrict__ Bt,
    const float* __restrict__ bias,
    u16* __restrict__ q, u16* __restrict__ k, u16* __restrict__ vt,
    float* __restrict__ outF)
{
    __shared__ __align__(16) char AsB[2][16384];
    __shared__ __align__(16) char BsB[2][16384];
    const int tid = threadIdx.x;
    const int l = tid & 63, li = l & 15, lg = l >> 4;
    const int w = tid >> 6, wm = w >> 1, wn = w & 1;
    const int m0 = blockIdx.y * 128, n0 = blockIdx.x * 128;
    const char* Ab = At + (size_t)blockIdx.y * (16 * 16384);
    const char* Bb = Bt + (size_t)blockIdx.x * (16 * 16384);

    f32x4 acc[4][4];
    #pragma unroll
    for (int i = 0; i < 4; ++i)
        #pragma unroll
        for (int j = 0; j < 4; ++j) acc[i][j] = (f32x4){0.f, 0.f, 0.f, 0.f};

    // ---- prologue: DMA tile 0 into buf 0 ----
    #pragma unroll
    for (int i = 0; i < 4; ++i) {
        gll16(Ab + w * 4096 + i * 1024 + l * 16, &AsB[0][w * 4096 + i * 1024]);
        gll16(Bb + w * 4096 + i * 1024 + l * 16, &BsB[0][w * 4096 + i * 1024]);
    }
    asm volatile("s_waitcnt vmcnt(0)" ::: "memory");
    __syncthreads();

    for (int kt = 0; kt < 16; ++kt) {
        const int cur = kt & 1;
        if (kt + 1 < 16) {
            const char* An = Ab + (kt + 1) * 16384;
            const char* Bn = Bb + (kt + 1) * 16384;
            #pragma unroll
            for (int i = 0; i < 4; ++i) {
                gll16(An + w * 4096 + i * 1024 + l * 16, &AsB[cur ^ 1][w * 4096 + i * 1024]);
                gll16(Bn + w * 4096 + i * 1024 + l * 16, &BsB[cur ^ 1][w * 4096 + i * 1024]);
            }
        }
        #pragma unroll
        for (int kc = 0; kc < 2; ++kc) {
            const int key = ((kc * 4 + lg) ^ (li & 7)) << 4;
            bf16x8 a[4], b[4];
            #pragma unroll
            for (int f = 0; f < 4; ++f)
                a[f] = *(const bf16x8*)&AsB[cur][(wm * 64 + f * 16 + li) * 128 + key];
            #pragma unroll
            for (int f = 0; f < 4; ++f)
                b[f] = *(const bf16x8*)&BsB[cur][(wn * 64 + f * 16 + li) * 128 + key];
            #pragma unroll
            for (int mi = 0; mi < 4; ++mi)
                #pragma unroll
                for (int ni = 0; ni < 4; ++ni)
                    acc[mi][ni] = __builtin_amdgcn_mfma_f32_16x16x32_bf16(a[mi], b[ni], acc[mi][ni], 0, 0, 0);
        }
        asm volatile("s_waitcnt vmcnt(0)" ::: "memory");
        __syncthreads();
    }

    const int mb = m0 + wm * 64;
    const int nb0 = n0 + wn * 64;
    if constexpr (EPI == 0) {
        const int part = n0 >> 10;
        if (part < 2) {
            u16* dst = (part == 0) ? q : k;
            const float scl = (part == 0) ? QSCALE : 1.0f;
            #pragma unroll
            for (int mi = 0; mi < 4; ++mi)
                #pragma unroll
                for (int r = 0; r < 4; ++r) {
                    const int m = mb + mi * 16 + lg * 4 + r;
                    const int bb = m >> 11, t = m & 2047;
                    #pragma unroll
                    for (int ni = 0; ni < 4; ++ni) {
                        const int n = nb0 + ni * 16 + li;
                        const int c = n & 1023;
                        const int h = c >> 6, d = c & 63;
                        const float val = (acc[mi][ni][r] + bias[n]) * scl;
                        dst[(((bb << 4) + h) * T_ + t) * DH + d] = f2bf(val);
                    }
                }
        } else {
            // V transposed: vt[((b*16+h)*64 + d)*2048 + t]
            #pragma unroll
            for (int mi = 0; mi < 4; ++mi) {
                const int m = mb + mi * 16 + lg * 4;
                const int bb = m >> 11, t0 = m & 2047;
                #pragma unroll
                for (int ni = 0; ni < 4; ++ni) {
                    const int n = nb0 + ni * 16 + li;
                    const int c = n & 1023;
                    const int h = c >> 6, d = c & 63;
                    const float bz = bias[n];
                    u32 w0 = pkbf(acc[mi][ni][0] + bz, acc[mi][ni][1] + bz);
                    u32 w1 = pkbf(acc[mi][ni][2] + bz, acc[mi][ni][3] + bz);
                    *(uint2*)&vt[(((bb << 4) + h) * 64 + d) * (size_t)T_ + t0] = make_uint2(w0, w1);
                }
            }
        }
    } else {
        #pragma unroll
        for (int mi = 0; mi < 4; ++mi)
            #pragma unroll
            for (int r = 0; r < 4; ++r) {
                const int m = mb + mi * 16 + lg * 4 + r;
                #pragma unroll
                for (int ni = 0; ni < 4; ++ni) {
                    const int n = nb0 + ni * 16 + li;
                    outF[m * 1024 + n] = acc[mi][ni][r] + bias[n];
                }
            }
    }
}

// ---------------- MFMA flash attention v13: swapped-QK + 32 q-rows per wave ----------------
// 256 threads (4 waves), Q-tile 128 (wave w owns rows w*32..w*32+31; lane li holds q-rows
// {wq0+li, wq0+16+li}). KV tile 64, dbuf K/V LDS, grid (32 bh, 16 slots).
// K/V fragment LDS reads are shared by both row-halves -> staging+barriers halve per work.
// Lane-local softmax (2 rows/lane), defer-max, exp2, ds_write_b64 P, setprio.
__global__ __launch_bounds__(256, 2) void flash_attn(
    const u16* __restrict__ Q, const u16* __restrict__ K,
    const u16* __restrict__ Vt, char* __restrict__ Yt)
{
    __shared__ __align__(16) char KsB[2][8192];
    __shared__ __align__(16) char VsB[2][8192];
    __shared__ __align__(16) char PsB[4][4096];   // per-wave P: 32 rows x 128B

    const int bh = blockIdx.x;
    const int slot = blockIdx.y;
    const int qt = (slot & 1) ? (15 - (slot >> 1)) : (slot >> 1);   // q-tile-128 index
    const int tid = threadIdx.x;
    const int w  = tid >> 6;
    const int l  = tid & 63;
    const int li = l & 15, lg = l >> 4;
    const u16* Qb = Q  + (size_t)bh * (T_ * DH);
    const u16* Kb = K  + (size_t)bh * (T_ * DH);
    const u16* Vb = Vt + (size_t)bh * (T_ * DH);   // rows (d) of length T_
    const int srow = tid >> 3;   // 0..31
    const int sseg = tid & 7;    // 16B segment
    char* Pw = PsB[w];
    const int b = bh >> 4, hd = bh & 15;
    const int skey = (srow & 7) << 4;   // (srow+32)&7 == srow&7
    const int rdkey = (li & 7) << 4;

    const int qtb = qt * 128;
    const int wq0 = qtb + w * 32;
    const int q_row0 = wq0 + li;         // h=0 lane row
    const int q_row1 = wq0 + 16 + li;    // h=1 lane row
    const int nkv = 2 * qt + 2;                      // tiles staged by the block
    const int wnkv = ((wq0 + 31) >> 6) + 1;          // tiles this wave actually needs

    bf16x8 qa0[2], qa1[2];
    qa0[0] = *(const bf16x8*)(Qb + q_row0 * 64 + 0  + lg * 8);
    qa0[1] = *(const bf16x8*)(Qb + q_row0 * 64 + 32 + lg * 8);
    qa1[0] = *(const bf16x8*)(Qb + q_row1 * 64 + 0  + lg * 8);
    qa1[1] = *(const bf16x8*)(Qb + q_row1 * 64 + 32 + lg * 8);

    f32x4 o0[4], o1[4];   // o_h[nb][r] = O[q_row_h][d=nb*16+lg*4+r]
    #pragma unroll
    for (int nb = 0; nb < 4; ++nb) {
        o0[nb] = (f32x4){0.f, 0.f, 0.f, 0.f};
        o1[nb] = (f32x4){0.f, 0.f, 0.f, 0.f};
    }
    float m0 = -INFINITY, m1 = -INFINITY, l0 = 0.f, l1 = 0.f;

    uint4 kr0, kr1, vr0, vr1;
    // ---- prologue: stage tile 0 into buf 0 (rows srow and srow+32) ----
    kr0 = *(const uint4*)(Kb + srow * 64 + sseg * 8);
    kr1 = *(const uint4*)(Kb + (srow + 32) * 64 + sseg * 8);
    vr0 = *(const uint4*)(Vb + (size_t)srow * T_ + sseg * 8);
    vr1 = *(const uint4*)(Vb + (size_t)(srow + 32) * T_ + sseg * 8);
    *(uint4*)&KsB[0][srow * 128        + ((sseg << 4) ^ skey)] = kr0;
    *(uint4*)&KsB[0][(srow + 32) * 128 + ((sseg << 4) ^ skey)] = kr1;
    *(uint4*)&VsB[0][srow * 128        + ((sseg << 4) ^ skey)] = vr0;
    *(uint4*)&VsB[0][(srow + 32) * 128 + ((sseg << 4) ^ skey)] = vr1;
    __syncthreads();

    for (int j = 0; j < nkv; ++j) {
        const int cur = j & 1;
        const bool has_next = (j + 1 < nkv);
        const bool active = (j < wnkv);
        // ---- issue next tile's global loads (latency hides under compute) ----
        if (has_next) {
            const int t0 = (j + 1) * 64;
            kr0 = *(const uint4*)(Kb + (t0 + srow) * 64 + sseg * 8);
            kr1 = *(const uint4*)(Kb + (t0 + srow + 32) * 64 + sseg * 8);
            vr0 = *(const uint4*)(Vb + (size_t)srow * T_ + t0 + sseg * 8);
            vr1 = *(const uint4*)(Vb + (size_t)(srow + 32) * T_ + t0 + sseg * 8);
        }
        if (active) {
            // ---- S^T = K.Q^T for both row-halves; kb shared ----
            const char* Kc = KsB[cur];
            f32x4 s0[4], s1[4];
            __builtin_amdgcn_s_setprio(1);
            #pragma unroll
            for (int f = 0; f < 4; ++f) {
                s0[f] = (f32x4){0.f, 0.f, 0.f, 0.f};
                s1[f] = (f32x4){0.f, 0.f, 0.f, 0.f};
                #pragma unroll
                for (int c = 0; c < 2; ++c) {
                    bf16x8 kb = *(const bf16x8*)&Kc[(f * 16 + li) * 128 + ((c * 64 + lg * 16) ^ rdkey)];
                    s0[f] = __builtin_amdgcn_mfma_f32_16x16x32_bf16(kb, qa0[c], s0[f], 0, 0, 0);
                    s1[f] = __builtin_amdgcn_mfma_f32_16x16x32_bf16(kb, qa1[c], s1[f], 0, 0, 0);
                }
            }
            __builtin_amdgcn_s_setprio(0);
            // ---- causal mask on diagonal tiles ----
            if ((j + 1) * 64 > wq0) {
                const int kbase = j * 64 + lg * 4;
                #pragma unroll
                for (int f = 0; f < 4; ++f)
                    #pragma unroll
                    for (int r = 0; r < 4; ++r) {
                        const int kk = kbase + f * 16 + r;
                        if (kk > q_row0) s0[f][r] = -INFINITY;
                        if (kk > q_row1) s1[f][r] = -INFINITY;
                    }
            }
            // ---- softmax: lane-local max; cross-reduce only on rescale ----
            float lm0 = s0[0][0], lm1 = s1[0][0];
            #pragma unroll
            for (int f = 0; f < 4; ++f)
                #pragma unroll
                for (int r = 0; r < 4; ++r) {
                    lm0 = fmaxf(lm0, s0[f][r]);
                    lm1 = fmaxf(lm1, s1[f][r]);
                }
            if (!__all((lm0 <= m0 + DEFER_THR) & (lm1 <= m1 + DEFER_THR))) {
                float t0r = lm0, t1r = lm1;
                t0r = fmaxf(t0r, __shfl_xor(t0r, 16));
                t0r = fmaxf(t0r, __shfl_xor(t0r, 32));
                t1r = fmaxf(t1r, __shfl_xor(t1r, 16));
                t1r = fmaxf(t1r, __shfl_xor(t1r, 32));
                const float mn0 = fmaxf(m0, t0r), mn1 = fmaxf(m1, t1r);
                const float c0 = exp2f(m0 - mn0), c1 = exp2f(m1 - mn1);
                m0 = mn0; m1 = mn1;
                l0 *= c0; l1 *= c1;
                #pragma unroll
                for (int nb = 0; nb < 4; ++nb)
                    #pragma unroll
                    for (int r = 0; r < 4; ++r) {
                        o0[nb][r] *= c0;
                        o1[nb][r] *= c1;
                    }
            }
            // ---- P = exp2(S - m); write both halves (ds_write_b64 each) ----
            #pragma unroll
            for (int f = 0; f < 4; ++f) {
                float a0 = exp2f(s0[f][0] - m0), a1 = exp2f(s0[f][1] - m0);
                float a2 = exp2f(s0[f][2] - m0), a3 = exp2f(s0[f][3] - m0);
                l0 += (a0 + a1) + (a2 + a3);
                uint2 pk = make_uint2(pkbf(a0, a1), pkbf(a2, a3));
                *(uint2*)&Pw[li * 128 + ((f * 32 + lg * 8) ^ rdkey)] = pk;
                float b0 = exp2f(s1[f][0] - m1), b1 = exp2f(s1[f][1] - m1);
                float b2 = exp2f(s1[f][2] - m1), b3 = exp2f(s1[f][3] - m1);
                l1 += (b0 + b1) + (b2 + b3);
                uint2 qk2 = make_uint2(pkbf(b0, b1), pkbf(b2, b3));
                *(uint2*)&Pw[(16 + li) * 128 + ((f * 32 + lg * 8) ^ rdkey)] = qk2;
            }
        }
        // ---- write prefetched K/V into the other buffer ----
        if (has_next) {
            *(uint4*)&KsB[cur ^ 1][srow * 128        + ((sseg << 4) ^ skey)] = kr0;
            *(uint4*)&KsB[cur ^ 1][(srow + 32) * 128 + ((sseg << 4) ^ skey)] = kr1;
            *(uint4*)&VsB[cur ^ 1][srow * 128        + ((sseg << 4) ^ skey)] = vr0;
            *(uint4*)&VsB[cur ^ 1][(srow + 32) * 128 + ((sseg << 4) ^ skey)] = vr1;
        }
        // ---- O^T += V^T.P^T for both halves; vb shared ----
        if (active) {
            const char* Vc = VsB[cur];
            __builtin_amdgcn_s_setprio(1);
            #pragma unroll
            for (int c = 0; c < 2; ++c) {
                bf16x8 pa0 = *(const bf16x8*)&Pw[li * 128        + ((c * 64 + lg * 16) ^ rdkey)];
                bf16x8 pa1 = *(const bf16x8*)&Pw[(16 + li) * 128 + ((c * 64 + lg * 16) ^ rdkey)];
                #pragma unroll
                for (int nb = 0; nb < 4; ++nb) {
                    bf16x8 vb = *(const bf16x8*)&Vc[(nb * 16 + li) * 128 + ((c * 64 + lg * 16) ^ rdkey)];
                    o0[nb] = __builtin_amdgcn_mfma_f32_16x16x32_bf16(vb, pa0, o0[nb], 0, 0, 0);
                    o1[nb] = __builtin_amdgcn_mfma_f32_16x16x32_bf16(vb, pa1, o1[nb], 0, 0, 0);
                }
            }
            __builtin_amdgcn_s_setprio(0);
        }
        __syncthreads();
    }

    // ---- epilogue: cross-reduce l, normalize, write Y (tiled-swizzled, 8B stores) ----
    l0 += __shfl_xor(l0, 16); l0 += __shfl_xor(l0, 32);
    l1 += __shfl_xor(l1, 16); l1 += __shfl_xor(l1, 32);
    const float i0 = 1.0f / l0, i1 = 1.0f / l1;
    // matrix row = b*2048 + qtb + w*32 + h*16 + li  ->  mt = b*16 + qt
    char* ytile = Yt + ((size_t)((b * 16 + qt) * 16 + hd)) * 16384;
    #pragma unroll
    for (int h = 0; h < 2; ++h) {
        const int r128 = w * 32 + h * 16 + li;
        const int rk = (r128 & 7) << 4;
        char* yrow = ytile + r128 * 128;
        const float inv = h ? i1 : i0;
        const f32x4* oo = h ? o1 : o0;
        #pragma unroll
        for (int nb = 0; nb < 4; ++nb) {
            const int seg = 2 * nb + (lg >> 1);
            uint2 pk = make_uint2(pkbf(oo[nb][0] * inv, oo[nb][1] * inv),
                                  pkbf(oo[nb][2] * inv, oo[nb][3] * inv));
            *(uint2*)&yrow[((seg << 4) ^ rk) + (lg & 1) * 8] = pk;
        }
    }
}

extern "C" void kernel_launch(void* const* d_in, const int* in_sizes, int n_in,
                              void* d_out, int out_size, void* d_ws, size_t ws_size,
                              hipStream_t stream) {
    const float* x      = (const float*)d_in[0];
    const float* W_attn = (const float*)d_in[1];
    const float* b_attn = (const float*)d_in[2];
    const float* W_proj = (const float*)d_in[3];
    const float* b_proj = (const float*)d_in[4];
    float* out = (float*)d_out;

    char* ws = (char*)d_ws;
    u16* q   = (u16*)ws;                          // [B,H,T,D] bf16, 8 MB
    u16* k   = (u16*)(ws + (8u << 20));           // [B,H,T,D] 8 MB
    u16* vt  = (u16*)(ws + (16u << 20));          // [B,H,D,T] 8 MB
    char* xb = ws + (24u << 20);                  // x tiled bf16 8 MB; REUSED as Yt after qkv
    char* wab = ws + (32u << 20);                 // W_attn tiled bf16 6 MB
    char* wpb = ws + (38u << 20);                 // W_proj tiled bf16 2 MB

    cvt_all<<<4096, 256, 0, stream>>>(x, W_attn, W_proj, (u16*)xb, (u16*)wab, (u16*)wpb);
    gemm_lds<0><<<dim3(24, 32), 256, 0, stream>>>(xb, wab, b_attn, q, k, vt, nullptr);
    flash_attn<<<dim3(32, 16), 256, 0, stream>>>(q, k, vt, xb /* Yt */);
    gemm_lds<1><<<dim3(8, 32), 256, 0, stream>>>(xb /* Yt */, wpb, b_proj,
                                                 nullptr, nullptr, nullptr, out);
}

// Round 14
// 123.043 us; speedup vs baseline: 1.0830x; 1.0830x over previous
//
#include <hip/hip_runtime.h>

typedef unsigned int u32;
typedef unsigned short u16;
typedef __attribute__((ext_vector_type(8))) short bf16x8;
typedef __attribute__((ext_vector_type(4))) float f32x4;

#define T_ 2048
#define HEADS 16
#define DH 64
#define NQ (2 * HEADS * T_ * DH)  // 4194304 elems per tensor

__device__ __forceinline__ u16 f2bf(float f) {
    union { float f; u32 u; } x; x.f = f;
    return (u16)((x.u + 0x7fffu + ((x.u >> 16) & 1u)) >> 16);
}
// packed f32x2 -> bf16x2 (RNE), single HW instruction
__device__ __forceinline__ u32 pkbf(float lo, float hi) {
    u32 r;
    asm("v_cvt_pk_bf16_f32 %0, %1, %2" : "=v"(r) : "v"(lo), "v"(hi));
    return r;
}
// async global->LDS, 16B per lane: LDS dest = wave-uniform base + lane*16
__device__ __forceinline__ void gll16(const void* g, void* l) {
    __builtin_amdgcn_global_load_lds(
        (const __attribute__((address_space(1))) void*)g,
        (__attribute__((address_space(3))) void*)l, 16, 0, 0);
}

// q pre-scaled by 1/sqrt(64) * log2(e) so softmax runs in exp2 domain
#define QSCALE 0.18033688011112042f
#define DEFER_THR 8.0f

// ============ fused fp32 [rows][1024] -> bf16 tile-major pre-swizzled (3 tensors) ============
// Element (m,k): tile (mt=m>>7, kt=k>>6), r=m&127, seg=(k&63)>>3, e=k&7.
// byte off = (mt*16+kt)*16384 + r*128 + ((seg ^ (r&7))<<4) + e*2.
#define NG_X  (4096 * 128)
#define NG_WA (3072 * 128)
__global__ __launch_bounds__(256) void cvt_all(
    const float* __restrict__ x, const float* __restrict__ wa,
    const float* __restrict__ wp,
    u16* __restrict__ dx, u16* __restrict__ dwa, u16* __restrict__ dwp)
{
    int gid = blockIdx.x * 256 + threadIdx.x;
    const float* src; u16* dst;
    if (gid < NG_X)                { src = x;  dst = dx; }
    else if (gid < NG_X + NG_WA)   { src = wa; dst = dwa; gid -= NG_X; }
    else                           { src = wp; dst = dwp; gid -= NG_X + NG_WA; }
    const int m = gid >> 7, s = gid & 127;          // s: 8-elem group within row
    const int kt = s >> 3, seg = s & 7;
    const float4 a0 = *(const float4*)&src[m * 1024 + s * 8];
    const float4 a1 = *(const float4*)&src[m * 1024 + s * 8 + 4];
    uint4 t;
    t.x = pkbf(a0.x, a0.y); t.y = pkbf(a0.z, a0.w);
    t.z = pkbf(a1.x, a1.y); t.w = pkbf(a1.z, a1.w);
    const int mt = m >> 7, r = m & 127;
    char* d = (char*)dst + ((size_t)(mt * 16 + kt)) * 16384
              + r * 128 + ((seg ^ (r & 7)) << 4);
    *(uint4*)d = t;
}

// ================= MFMA GEMM via global_load_lds (m97 structure) =================
// A, B: bf16 tile-major pre-swizzled (cvt layout). 128x128 tile, BK=64,
// 4 waves (2x2), 4x4 frags mfma_f32_16x16x32_bf16, explicit LDS double-buffer.
// EPI 0: qkv epilogue (q [B,H,T,D] scaled QSCALE; k,v as per-(bh,tile64) 8KB
//        LDS-image blobs so flash can stage them with global_load_lds)
// EPI 1: proj epilogue (fp32 out + bias)
template<int EPI>
__global__ __launch_bounds__(256, 2) void gemm_lds(
    const char* __restrict__ At, const char* __restrict__ Bt,
    const float* __restrict__ bias,
    u16* __restrict__ q, char* __restrict__ kimg, char* __restrict__ vimg,
    float* __restrict__ outF)
{
    __shared__ __align__(16) char AsB[2][16384];
    __shared__ __align__(16) char BsB[2][16384];
    const int tid = threadIdx.x;
    const int l = tid & 63, li = l & 15, lg = l >> 4;
    const int w = tid >> 6, wm = w >> 1, wn = w & 1;
    const int m0 = blockIdx.y * 128, n0 = blockIdx.x * 128;
    const char* Ab = At + (size_t)blockIdx.y * (16 * 16384);
    const char* Bb = Bt + (size_t)blockIdx.x * (16 * 16384);

    f32x4 acc[4][4];
    #pragma unroll
    for (int i = 0; i < 4; ++i)
        #pragma unroll
        for (int j = 0; j < 4; ++j) acc[i][j] = (f32x4){0.f, 0.f, 0.f, 0.f};

    // ---- prologue: DMA tile 0 into buf 0 ----
    #pragma unroll
    for (int i = 0; i < 4; ++i) {
        gll16(Ab + w * 4096 + i * 1024 + l * 16, &AsB[0][w * 4096 + i * 1024]);
        gll16(Bb + w * 4096 + i * 1024 + l * 16, &BsB[0][w * 4096 + i * 1024]);
    }
    asm volatile("s_waitcnt vmcnt(0)" ::: "memory");
    __syncthreads();

    for (int kt = 0; kt < 16; ++kt) {
        const int cur = kt & 1;
        if (kt + 1 < 16) {
            const char* An = Ab + (kt + 1) * 16384;
            const char* Bn = Bb + (kt + 1) * 16384;
            #pragma unroll
            for (int i = 0; i < 4; ++i) {
                gll16(An + w * 4096 + i * 1024 + l * 16, &AsB[cur ^ 1][w * 4096 + i * 1024]);
                gll16(Bn + w * 4096 + i * 1024 + l * 16, &BsB[cur ^ 1][w * 4096 + i * 1024]);
            }
        }
        #pragma unroll
        for (int kc = 0; kc < 2; ++kc) {
            const int key = ((kc * 4 + lg) ^ (li & 7)) << 4;
            bf16x8 a[4], b[4];
            #pragma unroll
            for (int f = 0; f < 4; ++f)
                a[f] = *(const bf16x8*)&AsB[cur][(wm * 64 + f * 16 + li) * 128 + key];
            #pragma unroll
            for (int f = 0; f < 4; ++f)
                b[f] = *(const bf16x8*)&BsB[cur][(wn * 64 + f * 16 + li) * 128 + key];
            #pragma unroll
            for (int mi = 0; mi < 4; ++mi)
                #pragma unroll
                for (int ni = 0; ni < 4; ++ni)
                    acc[mi][ni] = __builtin_amdgcn_mfma_f32_16x16x32_bf16(a[mi], b[ni], acc[mi][ni], 0, 0, 0);
        }
        asm volatile("s_waitcnt vmcnt(0)" ::: "memory");
        __syncthreads();
    }

    const int mb = m0 + wm * 64;
    const int nb0 = n0 + wn * 64;
    if constexpr (EPI == 0) {
        const int part = n0 >> 10;   // blocks never straddle a 1024 boundary
        if (part == 0) {
            // q: [B,H,T,D], scaled by QSCALE
            #pragma unroll
            for (int mi = 0; mi < 4; ++mi)
                #pragma unroll
                for (int r = 0; r < 4; ++r) {
                    const int m = mb + mi * 16 + lg * 4 + r;
                    const int bb = m >> 11, t = m & 2047;
                    #pragma unroll
                    for (int ni = 0; ni < 4; ++ni) {
                        const int n = nb0 + ni * 16 + li;
                        const int c = n & 1023;
                        const int h = c >> 6, d = c & 63;
                        const float val = (acc[mi][ni][r] + bias[n]) * QSCALE;
                        q[(((bb << 4) + h) * T_ + t) * DH + d] = f2bf(val);
                    }
                }
        } else if (part == 1) {
            // k image: [bh][tile j][row tr][seg swizzled] — tr = t&63, col = d
            #pragma unroll
            for (int mi = 0; mi < 4; ++mi)
                #pragma unroll
                for (int r = 0; r < 4; ++r) {
                    const int m = mb + mi * 16 + lg * 4 + r;
                    const int bb = m >> 11, t = m & 2047;
                    const int j = t >> 6, tr = t & 63;
                    const int rk = (tr & 7) << 4;
                    char* tile = kimg + (((size_t)((bb << 4))) << 18) + j * 8192 + tr * 128;
                    #pragma unroll
                    for (int ni = 0; ni < 4; ++ni) {
                        const int n = nb0 + ni * 16 + li;
                        const int c = n & 1023;
                        const int h = c >> 6, d = c & 63;
                        const float val = acc[mi][ni][r] + bias[n];
                        *(u16*)&tile[((size_t)h << 18) + ((((d >> 3) << 4)) ^ rk) + (d & 7) * 2] = f2bf(val);
                    }
                }
        } else {
            // v image: [bh][tile j][row d][cols t] — row = d, col tc = t&63; uint2 over r
            #pragma unroll
            for (int mi = 0; mi < 4; ++mi) {
                const int m = mb + mi * 16 + lg * 4;
                const int bb = m >> 11, t0 = m & 2047;
                const int j = t0 >> 6, tc = t0 & 63;
                const int sege = (((tc >> 3) & 7) << 4);
                #pragma unroll
                for (int ni = 0; ni < 4; ++ni) {
                    const int n = nb0 + ni * 16 + li;
                    const int c = n & 1023;
                    const int h = c >> 6, d = c & 63;
                    const float bz = bias[n];
                    u32 w0 = pkbf(acc[mi][ni][0] + bz, acc[mi][ni][1] + bz);
                    u32 w1 = pkbf(acc[mi][ni][2] + bz, acc[mi][ni][3] + bz);
                    char* dst = vimg + (((size_t)((bb << 4) + h)) << 18) + j * 8192
                              + d * 128 + (sege ^ ((d & 7) << 4)) + (tc & 7) * 2;
                    *(uint2*)dst = make_uint2(w0, w1);
                }
            }
        }
    } else {
        #pragma unroll
        for (int mi = 0; mi < 4; ++mi)
            #pragma unroll
            for (int r = 0; r < 4; ++r) {
                const int m = mb + mi * 16 + lg * 4 + r;
                #pragma unroll
                for (int ni = 0; ni < 4; ++ni) {
                    const int n = nb0 + ni * 16 + li;
                    outF[m * 1024 + n] = acc[mi][ni][r] + bias[n];
                }
            }
    }
}

// ---------------- MFMA flash attention v14: v12 + global_load_lds K/V staging ----------------
// 256 threads (4 waves), Q-tile 64, KV tile 64, grid (32 bh, 32 slots) alternating
// long/short. K/V tiles are pre-laid-out 8KB LDS images (from qkv epilogue) -> staged
// with 4 gll16 DMAs per thread, no ds_writes, no staging registers.
// Swapped-QK (S^T), lane-local softmax, defer-max, exp2, ds_write_b64 P, setprio.
__global__ __launch_bounds__(256, 2) void flash_attn(
    const u16* __restrict__ Q, const char* __restrict__ Kimg,
    const char* __restrict__ Vimg, char* __restrict__ Yt)
{
    __shared__ __align__(16) char KsB[2][8192];
    __shared__ __align__(16) char VsB[2][8192];
    __shared__ __align__(16) char PsB[4][2048];

    const int bh = blockIdx.x;
    const int slot = blockIdx.y;
    const int qt = (slot & 1) ? (31 - (slot >> 1)) : (slot >> 1);
    const int tid = threadIdx.x;
    const int w  = tid >> 6;
    const int l  = tid & 63;
    const int li = l & 15, lg = l >> 4;
    const u16* Qb = Q + (size_t)bh * (T_ * DH);
    const char* Kb = Kimg + ((size_t)bh << 18);   // 32 tiles x 8KB
    const char* Vb = Vimg + ((size_t)bh << 18);
    char* Pw = PsB[w];
    const int b = bh >> 4, h = bh & 15;
    const int rdkey = (li & 7) << 4;
    const int wseg = w * 2048;                     // this wave's 2KB DMA segment

    const int wq0 = qt * 64 + w * 16;
    const int q_row = wq0 + li;          // this lane's q row
    const int nkv = qt + 1;

    bf16x8 qa[2];
    qa[0] = *(const bf16x8*)(Qb + q_row * 64 + 0  + lg * 8);
    qa[1] = *(const bf16x8*)(Qb + q_row * 64 + 32 + lg * 8);

    f32x4 o[4];   // o[nb][r] = O[q=li][d=nb*16+lg*4+r]
    #pragma unroll
    for (int nb = 0; nb < 4; ++nb) o[nb] = (f32x4){0.f, 0.f, 0.f, 0.f};
    float m_r = -INFINITY, l_r = 0.f;    // lane-scalar (q-row li)

    // ---- prologue: DMA tile 0 into buf 0 ----
    #pragma unroll
    for (int i = 0; i < 2; ++i) {
        gll16(Kb + wseg + i * 1024 + l * 16, &KsB[0][wseg + i * 1024]);
        gll16(Vb + wseg + i * 1024 + l * 16, &VsB[0][wseg + i * 1024]);
    }
    asm volatile("s_waitcnt vmcnt(0)" ::: "memory");
    __syncthreads();

    for (int j = 0; j < nkv; ++j) {
        const int cur = j & 1;
        // ---- DMA next tile into the other buffer (read-done since last barrier) ----
        if (j + 1 < nkv) {
            const char* Kn = Kb + (j + 1) * 8192;
            const char* Vn = Vb + (j + 1) * 8192;
            #pragma unroll
            for (int i = 0; i < 2; ++i) {
                gll16(Kn + wseg + i * 1024 + l * 16, &KsB[cur ^ 1][wseg + i * 1024]);
                gll16(Vn + wseg + i * 1024 + l * 16, &VsB[cur ^ 1][wseg + i * 1024]);
            }
        }
        // ---- S^T = K.Q^T : s[f][r] = S[q=li][k = j*64 + f*16 + lg*4 + r] ----
        const char* Kc = KsB[cur];
        f32x4 s[4];
        __builtin_amdgcn_s_setprio(1);
        #pragma unroll
        for (int f = 0; f < 4; ++f) {
            s[f] = (f32x4){0.f, 0.f, 0.f, 0.f};
            #pragma unroll
            for (int c = 0; c < 2; ++c) {
                bf16x8 kb = *(const bf16x8*)&Kc[(f * 16 + li) * 128 + ((c * 64 + lg * 16) ^ rdkey)];
                s[f] = __builtin_amdgcn_mfma_f32_16x16x32_bf16(kb, qa[c], s[f], 0, 0, 0);
            }
        }
        __builtin_amdgcn_s_setprio(0);
        // ---- causal mask on diagonal tile (only j==qt can cross) ----
        if ((j + 1) * 64 > wq0) {
            const int kbase = j * 64 + lg * 4;
            #pragma unroll
            for (int f = 0; f < 4; ++f)
                #pragma unroll
                for (int r = 0; r < 4; ++r)
                    if (kbase + f * 16 + r > q_row) s[f][r] = -INFINITY;
        }
        // ---- softmax: lane-local max check; cross-reduce only on rescale ----
        float lm = s[0][0];
        #pragma unroll
        for (int f = 0; f < 4; ++f)
            #pragma unroll
            for (int r = 0; r < 4; ++r) lm = fmaxf(lm, s[f][r]);
        if (!__all(lm <= m_r + DEFER_THR)) {
            float tm = lm;
            tm = fmaxf(tm, __shfl_xor(tm, 16));
            tm = fmaxf(tm, __shfl_xor(tm, 32));
            const float mnew = fmaxf(m_r, tm);
            const float corr = exp2f(m_r - mnew);
            m_r = mnew;
            l_r *= corr;
            #pragma unroll
            for (int nb = 0; nb < 4; ++nb)
                #pragma unroll
                for (int r = 0; r < 4; ++r) o[nb][r] *= corr;
        }
        // ---- P = exp2(S - m), accumulate l, pack & write (4x ds_write_b64) ----
        #pragma unroll
        for (int f = 0; f < 4; ++f) {
            float p0 = exp2f(s[f][0] - m_r);
            float p1 = exp2f(s[f][1] - m_r);
            float p2 = exp2f(s[f][2] - m_r);
            float p3 = exp2f(s[f][3] - m_r);
            l_r += (p0 + p1) + (p2 + p3);
            uint2 pk = make_uint2(pkbf(p0, p1), pkbf(p2, p3));
            *(uint2*)&Pw[li * 128 + (((f * 32 + lg * 8)) ^ rdkey)] = pk;
        }
        // ---- O^T += V^T.P^T : o[nb][r] = O[q=li][d=nb*16+lg*4+r] ----
        const char* Vc = VsB[cur];
        __builtin_amdgcn_s_setprio(1);
        #pragma unroll
        for (int c = 0; c < 2; ++c) {
            bf16x8 pa = *(const bf16x8*)&Pw[li * 128 + ((c * 64 + lg * 16) ^ rdkey)];
            #pragma unroll
            for (int nb = 0; nb < 4; ++nb) {
                bf16x8 vb = *(const bf16x8*)&Vc[(nb * 16 + li) * 128 + ((c * 64 + lg * 16) ^ rdkey)];
                o[nb] = __builtin_amdgcn_mfma_f32_16x16x32_bf16(vb, pa, o[nb], 0, 0, 0);
            }
        }
        __builtin_amdgcn_s_setprio(0);
        __syncthreads();   // DMA drained (compiler) + all waves done with buffers
    }

    // ---- epilogue: cross-reduce l, normalize, write Y (tiled-swizzled, 8B stores) ----
    l_r += __shfl_xor(l_r, 16);
    l_r += __shfl_xor(l_r, 32);
    const float inv = 1.0f / l_r;
    // matrix row = b*2048 + qt*64 + w*16 + li  ->  mt = b*16 + (qt>>1)
    const int r128 = (qt & 1) * 64 + w * 16 + li;
    const int rk = (r128 & 7) << 4;
    char* yrow = Yt + ((size_t)((b * 16 + (qt >> 1)) * 16 + h)) * 16384 + r128 * 128;
    #pragma unroll
    for (int nb = 0; nb < 4; ++nb) {
        // d = nb*16 + lg*4 + r, r=0..3 -> seg = 2nb + (lg>>1), byte e0 = (lg&1)*8
        const int seg = 2 * nb + (lg >> 1);
        uint2 pk = make_uint2(pkbf(o[nb][0] * inv, o[nb][1] * inv),
                              pkbf(o[nb][2] * inv, o[nb][3] * inv));
        *(uint2*)&yrow[((seg << 4) ^ rk) + (lg & 1) * 8] = pk;
    }
}

extern "C" void kernel_launch(void* const* d_in, const int* in_sizes, int n_in,
                              void* d_out, int out_size, void* d_ws, size_t ws_size,
                              hipStream_t stream) {
    const float* x      = (const float*)d_in[0];
    const float* W_attn = (const float*)d_in[1];
    const float* b_attn = (const float*)d_in[2];
    const float* W_proj = (const float*)d_in[3];
    const float* b_proj = (const float*)d_in[4];
    float* out = (float*)d_out;

    char* ws = (char*)d_ws;
    u16* q    = (u16*)ws;                          // [B,H,T,D] bf16, 8 MB
    char* kimg = ws + (8u << 20);                  // [bh][tile64] 8KB images, 8 MB
    char* vimg = ws + (16u << 20);                 // [bh][tile64] 8KB images, 8 MB
    char* xb  = ws + (24u << 20);                  // x tiled bf16 8 MB; REUSED as Yt after qkv
    char* wab = ws + (32u << 20);                  // W_attn tiled bf16 6 MB
    char* wpb = ws + (38u << 20);                  // W_proj tiled bf16 2 MB

    cvt_all<<<4096, 256, 0, stream>>>(x, W_attn, W_proj, (u16*)xb, (u16*)wab, (u16*)wpb);
    gemm_lds<0><<<dim3(24, 32), 256, 0, stream>>>(xb, wab, b_attn, q, kimg, vimg, nullptr);
    flash_attn<<<dim3(32, 32), 256, 0, stream>>>(q, kimg, vimg, xb /* Yt */);
    gemm_lds<1><<<dim3(8, 32), 256, 0, stream>>>(xb /* Yt */, wpb, b_proj,
                                                 nullptr, nullptr, nullptr, out);
}

// Round 15
// 109.452 us; speedup vs baseline: 1.2175x; 1.1242x over previous
//
#include <hip/hip_runtime.h>

typedef unsigned int u32;
typedef unsigned short u16;
typedef __attribute__((ext_vector_type(8))) short bf16x8;
typedef __attribute__((ext_vector_type(4))) float f32x4;

#define T_ 2048
#define HEADS 16
#define DH 64
#define NQ (2 * HEADS * T_ * DH)  // 4194304 elems per tensor

__device__ __forceinline__ u16 f2bf(float f) {
    union { float f; u32 u; } x; x.f = f;
    return (u16)((x.u + 0x7fffu + ((x.u >> 16) & 1u)) >> 16);
}
// packed f32x2 -> bf16x2 (RNE), single HW instruction
__device__ __forceinline__ u32 pkbf(float lo, float hi) {
    u32 r;
    asm("v_cvt_pk_bf16_f32 %0, %1, %2" : "=v"(r) : "v"(lo), "v"(hi));
    return r;
}
// async global->LDS, 16B per lane: LDS dest = wave-uniform base + lane*16
__device__ __forceinline__ void gll16(const void* g, void* l) {
    __builtin_amdgcn_global_load_lds(
        (const __attribute__((address_space(1))) void*)g,
        (__attribute__((address_space(3))) void*)l, 16, 0, 0);
}

// q pre-scaled by 1/sqrt(64) * log2(e) so softmax runs in exp2 domain
#define QSCALE 0.18033688011112042f
#define DEFER_THR 8.0f

// ============ fused fp32 [rows][1024] -> bf16 tile-major pre-swizzled (3 tensors) ============
// Element (m,k): tile (mt=m>>7, kt=k>>6), r=m&127, seg=(k&63)>>3, e=k&7.
// byte off = (mt*16+kt)*16384 + r*128 + ((seg ^ (r&7))<<4) + e*2.
#define NG_X  (4096 * 128)
#define NG_WA (3072 * 128)
__global__ __launch_bounds__(256) void cvt_all(
    const float* __restrict__ x, const float* __restrict__ wa,
    const float* __restrict__ wp,
    u16* __restrict__ dx, u16* __restrict__ dwa, u16* __restrict__ dwp)
{
    int gid = blockIdx.x * 256 + threadIdx.x;
    const float* src; u16* dst;
    if (gid < NG_X)                { src = x;  dst = dx; }
    else if (gid < NG_X + NG_WA)   { src = wa; dst = dwa; gid -= NG_X; }
    else                           { src = wp; dst = dwp; gid -= NG_X + NG_WA; }
    const int m = gid >> 7, s = gid & 127;          // s: 8-elem group within row
    const int kt = s >> 3, seg = s & 7;
    const float4 a0 = *(const float4*)&src[m * 1024 + s * 8];
    const float4 a1 = *(const float4*)&src[m * 1024 + s * 8 + 4];
    uint4 t;
    t.x = pkbf(a0.x, a0.y); t.y = pkbf(a0.z, a0.w);
    t.z = pkbf(a1.x, a1.y); t.w = pkbf(a1.z, a1.w);
    const int mt = m >> 7, r = m & 127;
    char* d = (char*)dst + ((size_t)(mt * 16 + kt)) * 16384
              + r * 128 + ((seg ^ (r & 7)) << 4);
    *(uint4*)d = t;
}

// ================= MFMA GEMM via global_load_lds (m97 structure, single-buffered) =================
// A, B: bf16 tile-major pre-swizzled (cvt layout). 128x128 tile, BK=64,
// 4 waves (2x2), 4x4 frags mfma_f32_16x16x32_bf16. Single 32KB LDS buffer,
// stage -> vmcnt(0) -> barrier -> compute -> barrier (m97's 874 TF schedule),
// launch_bounds(256,3) for 3 blocks/CU — cross-block wave overlap hides the drain (m114).
// EPI 0: qkv epilogue (q,k [B,H,T,D], q scaled QSCALE; v transposed [B,H,D,T])
// EPI 1: proj epilogue (fp32 out + bias)
template<int EPI>
__global__ __launch_bounds__(256, 3) void gemm_lds(
    const char* __restrict__ At, const char* __restrict__ Bt,
    const float* __restrict__ bias,
    u16* __restrict__ q, u16* __restrict__ k, u16* __restrict__ vt,
    float* __restrict__ outF)
{
    __shared__ __align__(16) char AsB[16384];
    __shared__ __align__(16) char BsB[16384];
    const int tid = threadIdx.x;
    const int l = tid & 63, li = l & 15, lg = l >> 4;
    const int w = tid >> 6, wm = w >> 1, wn = w & 1;
    const int m0 = blockIdx.y * 128, n0 = blockIdx.x * 128;
    const char* Ab = At + (size_t)blockIdx.y * (16 * 16384);
    const char* Bb = Bt + (size_t)blockIdx.x * (16 * 16384);

    f32x4 acc[4][4];
    #pragma unroll
    for (int i = 0; i < 4; ++i)
        #pragma unroll
        for (int j = 0; j < 4; ++j) acc[i][j] = (f32x4){0.f, 0.f, 0.f, 0.f};

    for (int kt = 0; kt < 16; ++kt) {
        // ---- stage tile kt (8 DMAs per wave, no registers) ----
        const char* An = Ab + kt * 16384;
        const char* Bn = Bb + kt * 16384;
        #pragma unroll
        for (int i = 0; i < 4; ++i) {
            gll16(An + w * 4096 + i * 1024 + l * 16, &AsB[w * 4096 + i * 1024]);
            gll16(Bn + w * 4096 + i * 1024 + l * 16, &BsB[w * 4096 + i * 1024]);
        }
        asm volatile("s_waitcnt vmcnt(0)" ::: "memory");
        __syncthreads();
        // ---- compute ----
        #pragma unroll
        for (int kc = 0; kc < 2; ++kc) {
            const int key = ((kc * 4 + lg) ^ (li & 7)) << 4;
            bf16x8 a[4], b[4];
            #pragma unroll
            for (int f = 0; f < 4; ++f)
                a[f] = *(const bf16x8*)&AsB[(wm * 64 + f * 16 + li) * 128 + key];
            #pragma unroll
            for (int f = 0; f < 4; ++f)
                b[f] = *(const bf16x8*)&BsB[(wn * 64 + f * 16 + li) * 128 + key];
            #pragma unroll
            for (int mi = 0; mi < 4; ++mi)
                #pragma unroll
                for (int ni = 0; ni < 4; ++ni)
                    acc[mi][ni] = __builtin_amdgcn_mfma_f32_16x16x32_bf16(a[mi], b[ni], acc[mi][ni], 0, 0, 0);
        }
        __syncthreads();   // LDS consumed; safe to restage next iteration
    }

    const int mb = m0 + wm * 64;
    const int nb0 = n0 + wn * 64;
    if constexpr (EPI == 0) {
        const int part = n0 >> 10;
        if (part < 2) {
            u16* dst = (part == 0) ? q : k;
            const float scl = (part == 0) ? QSCALE : 1.0f;
            #pragma unroll
            for (int mi = 0; mi < 4; ++mi)
                #pragma unroll
                for (int r = 0; r < 4; ++r) {
                    const int m = mb + mi * 16 + lg * 4 + r;
                    const int bb = m >> 11, t = m & 2047;
                    #pragma unroll
                    for (int ni = 0; ni < 4; ++ni) {
                        const int n = nb0 + ni * 16 + li;
                        const int c = n & 1023;
                        const int h = c >> 6, d = c & 63;
                        const float val = (acc[mi][ni][r] + bias[n]) * scl;
                        dst[(((bb << 4) + h) * T_ + t) * DH + d] = f2bf(val);
                    }
                }
        } else {
            // V transposed: vt[((b*16+h)*64 + d)*2048 + t]
            #pragma unroll
            for (int mi = 0; mi < 4; ++mi) {
                const int m = mb + mi * 16 + lg * 4;
                const int bb = m >> 11, t0 = m & 2047;
                #pragma unroll
                for (int ni = 0; ni < 4; ++ni) {
                    const int n = nb0 + ni * 16 + li;
                    const int c = n & 1023;
                    const int h = c >> 6, d = c & 63;
                    const float bz = bias[n];
                    u32 w0 = pkbf(acc[mi][ni][0] + bz, acc[mi][ni][1] + bz);
                    u32 w1 = pkbf(acc[mi][ni][2] + bz, acc[mi][ni][3] + bz);
                    *(uint2*)&vt[(((bb << 4) + h) * 64 + d) * (size_t)T_ + t0] = make_uint2(w0, w1);
                }
            }
        }
    } else {
        #pragma unroll
        for (int mi = 0; mi < 4; ++mi)
            #pragma unroll
            for (int r = 0; r < 4; ++r) {
                const int m = mb + mi * 16 + lg * 4 + r;
                #pragma unroll
                for (int ni = 0; ni < 4; ++ni) {
                    const int n = nb0 + ni * 16 + li;
                    outF[m * 1024 + n] = acc[mi][ni][r] + bias[n];
                }
            }
    }
}

// ---------------- MFMA flash attention v12 (best: 54.6us): swapped-QK, lane-local softmax ----------------
// 256 thr / 4 waves, Q-tile 64, KV tile 64, dbuf K/V LDS, grid (32 bh, 32 slots),
// conflict-free staging. mfma(kb,qa) computes S^T so each lane holds one q-row (li)
// with k-adjacent quads. P writes are 4x ds_write_b64; softmax m/l are lane scalars;
// defer-max skip path has ZERO cross-lane ops; rescale uses shfl_xor 16/32.
__global__ __launch_bounds__(256, 2) void flash_attn(
    const u16* __restrict__ Q, const u16* __restrict__ K,
    const u16* __restrict__ Vt, char* __restrict__ Yt)
{
    __shared__ __align__(16) char KsB[2][8192];
    __shared__ __align__(16) char VsB[2][8192];
    __shared__ __align__(16) char PsB[4][2048];

    const int bh = blockIdx.x;
    const int slot = blockIdx.y;
    const int qt = (slot & 1) ? (31 - (slot >> 1)) : (slot >> 1);
    const int tid = threadIdx.x;
    const int w  = tid >> 6;
    const int l  = tid & 63;
    const int li = l & 15, lg = l >> 4;
    const u16* Qb = Q  + (size_t)bh * (T_ * DH);
    const u16* Kb = K  + (size_t)bh * (T_ * DH);
    const u16* Vb = Vt + (size_t)bh * (T_ * DH);   // rows (d) of length T_
    const int srow = tid >> 3;   // 0..31
    const int sseg = tid & 7;    // 16B segment
    char* Pw = PsB[w];
    const int b = bh >> 4, h = bh & 15;
    const int skey = (srow & 7) << 4;   // (srow+32)&7 == srow&7
    const int rdkey = (li & 7) << 4;

    const int wq0 = qt * 64 + w * 16;
    const int q_row = wq0 + li;          // this lane's q row
    const int nkv = qt + 1;

    bf16x8 qa[2];
    qa[0] = *(const bf16x8*)(Qb + q_row * 64 + 0  + lg * 8);
    qa[1] = *(const bf16x8*)(Qb + q_row * 64 + 32 + lg * 8);

    f32x4 o[4];   // o[nb][r] = O[q=li][d=nb*16+lg*4+r]
    #pragma unroll
    for (int nb = 0; nb < 4; ++nb) o[nb] = (f32x4){0.f, 0.f, 0.f, 0.f};
    float m_r = -INFINITY, l_r = 0.f;    // lane-scalar (q-row li)

    uint4 kr0, kr1, vr0, vr1;
    // ---- prologue: stage tile 0 into buf 0 (rows srow and srow+32) ----
    kr0 = *(const uint4*)(Kb + srow * 64 + sseg * 8);
    kr1 = *(const uint4*)(Kb + (srow + 32) * 64 + sseg * 8);
    vr0 = *(const uint4*)(Vb + (size_t)srow * T_ + sseg * 8);
    vr1 = *(const uint4*)(Vb + (size_t)(srow + 32) * T_ + sseg * 8);
    *(uint4*)&KsB[0][srow * 128        + ((sseg << 4) ^ skey)] = kr0;
    *(uint4*)&KsB[0][(srow + 32) * 128 + ((sseg << 4) ^ skey)] = kr1;
    *(uint4*)&VsB[0][srow * 128        + ((sseg << 4) ^ skey)] = vr0;
    *(uint4*)&VsB[0][(srow + 32) * 128 + ((sseg << 4) ^ skey)] = vr1;
    __syncthreads();

    for (int j = 0; j < nkv; ++j) {
        const int cur = j & 1;
        const bool has_next = (j + 1 < nkv);
        // ---- issue next tile's global loads (latency hides under compute) ----
        if (has_next) {
            const int t0 = (j + 1) * 64;
            kr0 = *(const uint4*)(Kb + (t0 + srow) * 64 + sseg * 8);
            kr1 = *(const uint4*)(Kb + (t0 + srow + 32) * 64 + sseg * 8);
            vr0 = *(const uint4*)(Vb + (size_t)srow * T_ + t0 + sseg * 8);
            vr1 = *(const uint4*)(Vb + (size_t)(srow + 32) * T_ + t0 + sseg * 8);
        }
        // ---- S^T = K.Q^T : s[f][r] = S[q=li][k = j*64 + f*16 + lg*4 + r] ----
        const char* Kc = KsB[cur];
        f32x4 s[4];
        __builtin_amdgcn_s_setprio(1);
        #pragma unroll
        for (int f = 0; f < 4; ++f) {
            s[f] = (f32x4){0.f, 0.f, 0.f, 0.f};
            #pragma unroll
            for (int c = 0; c < 2; ++c) {
                bf16x8 kb = *(const bf16x8*)&Kc[(f * 16 + li) * 128 + ((c * 64 + lg * 16) ^ rdkey)];
                s[f] = __builtin_amdgcn_mfma_f32_16x16x32_bf16(kb, qa[c], s[f], 0, 0, 0);
            }
        }
        __builtin_amdgcn_s_setprio(0);
        // ---- causal mask on diagonal tile (only j==qt can cross) ----
        if ((j + 1) * 64 > wq0) {
            const int kbase = j * 64 + lg * 4;
            #pragma unroll
            for (int f = 0; f < 4; ++f)
                #pragma unroll
                for (int r = 0; r < 4; ++r)
                    if (kbase + f * 16 + r > q_row) s[f][r] = -INFINITY;
        }
        // ---- softmax: lane-local max check; cross-reduce only on rescale ----
        float lm = s[0][0];
        #pragma unroll
        for (int f = 0; f < 4; ++f)
            #pragma unroll
            for (int r = 0; r < 4; ++r) lm = fmaxf(lm, s[f][r]);
        if (!__all(lm <= m_r + DEFER_THR)) {
            float tm = lm;
            tm = fmaxf(tm, __shfl_xor(tm, 16));
            tm = fmaxf(tm, __shfl_xor(tm, 32));
            const float mnew = fmaxf(m_r, tm);
            const float corr = exp2f(m_r - mnew);
            m_r = mnew;
            l_r *= corr;
            #pragma unroll
            for (int nb = 0; nb < 4; ++nb)
                #pragma unroll
                for (int r = 0; r < 4; ++r) o[nb][r] *= corr;
        }
        // ---- P = exp2(S - m), accumulate l, pack & write (4x ds_write_b64) ----
        #pragma unroll
        for (int f = 0; f < 4; ++f) {
            float p0 = exp2f(s[f][0] - m_r);
            float p1 = exp2f(s[f][1] - m_r);
            float p2 = exp2f(s[f][2] - m_r);
            float p3 = exp2f(s[f][3] - m_r);
            l_r += (p0 + p1) + (p2 + p3);
            uint2 pk = make_uint2(pkbf(p0, p1), pkbf(p2, p3));
            *(uint2*)&Pw[li * 128 + (((f * 32 + lg * 8)) ^ rdkey)] = pk;
        }
        // ---- write prefetched K/V into the other buffer ----
        if (has_next) {
            *(uint4*)&KsB[cur ^ 1][srow * 128        + ((sseg << 4) ^ skey)] = kr0;
            *(uint4*)&KsB[cur ^ 1][(srow + 32) * 128 + ((sseg << 4) ^ skey)] = kr1;
            *(uint4*)&VsB[cur ^ 1][srow * 128        + ((sseg << 4) ^ skey)] = vr0;
            *(uint4*)&VsB[cur ^ 1][(srow + 32) * 128 + ((sseg << 4) ^ skey)] = vr1;
        }
        // ---- O^T += V^T.P^T : o[nb][r] = O[q=li][d=nb*16+lg*4+r] ----
        const char* Vc = VsB[cur];
        __builtin_amdgcn_s_setprio(1);
        #pragma unroll
        for (int c = 0; c < 2; ++c) {
            bf16x8 pa = *(const bf16x8*)&Pw[li * 128 + ((c * 64 + lg * 16) ^ rdkey)];
            #pragma unroll
            for (int nb = 0; nb < 4; ++nb) {
                bf16x8 vb = *(const bf16x8*)&Vc[(nb * 16 + li) * 128 + ((c * 64 + lg * 16) ^ rdkey)];
                o[nb] = __builtin_amdgcn_mfma_f32_16x16x32_bf16(vb, pa, o[nb], 0, 0, 0);
            }
        }
        __builtin_amdgcn_s_setprio(0);
        __syncthreads();
    }

    // ---- epilogue: cross-reduce l, normalize, write Y (tiled-swizzled, 8B stores) ----
    l_r += __shfl_xor(l_r, 16);
    l_r += __shfl_xor(l_r, 32);
    const float inv = 1.0f / l_r;
    // matrix row = b*2048 + qt*64 + w*16 + li  ->  mt = b*16 + (qt>>1)
    const int r128 = (qt & 1) * 64 + w * 16 + li;
    const int rk = (r128 & 7) << 4;
    char* yrow = Yt + ((size_t)((b * 16 + (qt >> 1)) * 16 + h)) * 16384 + r128 * 128;
    #pragma unroll
    for (int nb = 0; nb < 4; ++nb) {
        // d = nb*16 + lg*4 + r, r=0..3 -> seg = 2nb + (lg>>1), byte e0 = (lg&1)*8
        const int seg = 2 * nb + (lg >> 1);
        uint2 pk = make_uint2(pkbf(o[nb][0] * inv, o[nb][1] * inv),
                              pkbf(o[nb][2] * inv, o[nb][3] * inv));
        *(uint2*)&yrow[((seg << 4) ^ rk) + (lg & 1) * 8] = pk;
    }
}

extern "C" void kernel_launch(void* const* d_in, const int* in_sizes, int n_in,
                              void* d_out, int out_size, void* d_ws, size_t ws_size,
                              hipStream_t stream) {
    const float* x      = (const float*)d_in[0];
    const float* W_attn = (const float*)d_in[1];
    const float* b_attn = (const float*)d_in[2];
    const float* W_proj = (const float*)d_in[3];
    const float* b_proj = (const float*)d_in[4];
    float* out = (float*)d_out;

    char* ws = (char*)d_ws;
    u16* q   = (u16*)ws;                          // [B,H,T,D] bf16, 8 MB
    u16* k   = (u16*)(ws + (8u << 20));           // [B,H,T,D] 8 MB
    u16* vt  = (u16*)(ws + (16u << 20));          // [B,H,D,T] 8 MB
    char* xb = ws + (24u << 20);                  // x tiled bf16 8 MB; REUSED as Yt after qkv
    char* wab = ws + (32u << 20);                 // W_attn tiled bf16 6 MB
    char* wpb = ws + (38u << 20);                 // W_proj tiled bf16 2 MB

    cvt_all<<<4096, 256, 0, stream>>>(x, W_attn, W_proj, (u16*)xb, (u16*)wab, (u16*)wpb);
    gemm_lds<0><<<dim3(24, 32), 256, 0, stream>>>(xb, wab, b_attn, q, k, vt, nullptr);
    flash_attn<<<dim3(32, 32), 256, 0, stream>>>(q, k, vt, xb /* Yt */);
    gemm_lds<1><<<dim3(8, 32), 256, 0, stream>>>(xb /* Yt */, wpb, b_proj,
                                                 nullptr, nullptr, nullptr, out);
}